// Round 2
// baseline (140.834 us; speedup 1.0000x reference)
//
#include <hip/hip_runtime.h>

// BlurModel: 100x100 box filter (VALID) * 1e-4 over (8,3,1024,1024) f32,
// then where(v > 0.129, 1.0, v).  24 images 1024x1024 -> 925x925.
//
// Wave-autonomous design: each 64-lane wave owns a 64-col output strip x
// 78-row chunk. No LDS, no __syncthreads.
//   - vertical 100-row window: 3 running column sums per lane in registers
//     (lane owns input cols j0+l, j0+64+l, j0+128+l; seg = 163 cols)
//   - horizontal 100-col window: 3 interleaved wave inclusive scans
//     (__shfl_up), window = suffix(group0) + prefix(group1/2) via 2
//     variable-src shuffles.

#define KS      100
#define KVALF   1e-4f
#define THRESHF 0.129f
#define WW      1024
#define OH      925
#define OW      925
#define SW      64            // output cols per wave
#define NSTRIP  15            // ceil(925/64); last strip 29 cols
#define NCHUNK  12
#define RPC     78            // rows per chunk; last chunk 67
#define NIMG    24
#define NWAVES  (NIMG * NSTRIP * NCHUNK)   // 4320

__global__ __launch_bounds__(256) void blur_wave(const float* __restrict__ x,
                                                 float* __restrict__ out) {
    const int lane = threadIdx.x & 63;
    const int wid  = threadIdx.x >> 6;
    const int w    = blockIdx.x * 4 + wid;

    const int strip = w % NSTRIP;
    const int chunk = (w / NSTRIP) % NCHUNK;
    const int img   = w / (NSTRIP * NCHUNK);

    const int j0     = strip * SW;
    const int jcount = min(SW, OW - j0);    // 64, or 29 on last strip
    const int seg    = jcount + KS - 1;     // 163, or 128 on last strip
    const bool h2    = (128 + lane) < seg;  // lane has a group-2 slot

    const int r0 = chunk * RPC;
    const int r1 = min(OH, r0 + RPC);

    const float* __restrict__ xi = x + (size_t)img * WW * WW + j0;
    float* __restrict__ oi       = out + (size_t)img * OH * OW;

    // ---- init: vertical column sums over rows r0..r0+99 ----
    float cs0 = 0.f, cs1 = 0.f, cs2 = 0.f;
    for (int r = r0; r < r0 + KS; ++r) {
        const float* row = xi + (size_t)r * WW;
        cs0 += row[lane];
        cs1 += row[64 + lane];
        if (h2) cs2 += row[128 + lane];
    }

    for (int i = r0; i < r1; ++i) {
        // prefetch next-row slide operands; consumed after the scans
        const bool upd = (i + 1 < r1);
        float n0 = 0.f, n1 = 0.f, n2 = 0.f, o0 = 0.f, o1 = 0.f, o2 = 0.f;
        if (upd) {
            const float* rn = xi + (size_t)(i + KS) * WW;  // row entering window
            const float* ro = xi + (size_t)i * WW;         // row leaving window
            n0 = rn[lane];      o0 = ro[lane];
            n1 = rn[64 + lane]; o1 = ro[64 + lane];
            if (h2) { n2 = rn[128 + lane]; o2 = ro[128 + lane]; }
        }

        // ---- three interleaved 64-lane inclusive scans ----
        float s0 = cs0, s1 = cs1, s2 = cs2;
#pragma unroll
        for (int d = 1; d < 64; d <<= 1) {
            const float u0 = __shfl_up(s0, d, 64);
            const float u1 = __shfl_up(s1, d, 64);
            const float u2 = __shfl_up(s2, d, 64);
            if (lane >= d) { s0 += u0; s1 += u1; s2 += u2; }
        }
        const float T0 = __shfl(s0, 63, 64);   // group-0 total
        const float T1 = __shfl(s1, 63, 64);   // group-1 total

        // window(l) = sum of slots l..l+99
        //   group0 part: suffix from l  = T0 - (s0 - cs0)
        //   group1 part: l<28 -> S1_incl[l+35], l>=28 -> T1
        //   group2 part: l>=29 -> S2_incl[l-29]
        const float suf0 = T0 - (s0 - cs0);
        int srcA = lane + 35; if (srcA > 63) srcA = 63;
        int srcB = lane - 29; if (srcB < 0)  srcB = 0;
        const float a = __shfl(s1, srcA, 64);
        const float b = __shfl(s2, srcB, 64);

        float win;
        if (lane < 28)       win = suf0 + a;
        else if (lane == 28) win = suf0 + T1;
        else                 win = suf0 + T1 + b;

        if (lane < jcount) {
            const float v = KVALF * win;
            oi[(size_t)i * OW + (j0 + lane)] = (v > THRESHF) ? 1.0f : v;
        }

        // ---- slide the vertical window ----
        if (upd) { cs0 += n0 - o0; cs1 += n1 - o1; cs2 += n2 - o2; }
    }
}

extern "C" void kernel_launch(void* const* d_in, const int* in_sizes, int n_in,
                              void* d_out, int out_size, void* d_ws, size_t ws_size,
                              hipStream_t stream) {
    const float* x = (const float*)d_in[0];
    float* out     = (float*)d_out;
    blur_wave<<<dim3(NWAVES / 4), dim3(256), 0, stream>>>(x, out);
}

// Round 3
// 72.452 us; speedup vs baseline: 1.9438x; 1.9438x over previous
//
#include <hip/hip_runtime.h>
#include <hip/hip_fp16.h>

// BlurModel: 100x100 box * 1e-4 over (8,3,1024,1024) f32 -> (24,925,925),
// then where(v > 0.129, 1.0, v).
//
// Two-pass separable:
//   pass1: R[r][j] = sum_{dj<100} x[r][j+dj]   (fp16 workspace, 48 MiB)
//          one wave per input row: float4 loads, in-lane prefix(16) +
//          wave scan, R via prefix difference (fixed-offset shuffles).
//   pass2: W[i][j] = W[i-1][j] + R[i+99][j] - R[i-1][j]; out = thresh(1e-4*W)
//          pure streaming, no cross-lane ops, 4 cols/thread.

#define KS      100
#define KVALF   1e-4f
#define THRESHF 0.129f
#define WW      1024
#define HH      1024
#define OH      925
#define OW      925
#define NIMG    24
#define RSTRIDE 1024                    // halfs per R row
#define NROWS   (NIMG * HH)             // 24576
#define NC2     32
#define RP2     29                      // ceil(925/32)

// ---------------- pass 1 ----------------
__global__ __launch_bounds__(256) void pass1_rowwin(const float* __restrict__ x,
                                                    __half* __restrict__ R) {
    const int lane = (int)(threadIdx.x & 63);
    const int g    = (int)blockIdx.x * 4 + (int)(threadIdx.x >> 6);  // row 0..24575

    const float4* __restrict__ r4 = (const float4*)(x + (size_t)g * WW);
    const float4 v0 = r4[4 * lane + 0];
    const float4 v1 = r4[4 * lane + 1];
    const float4 v2 = r4[4 * lane + 2];
    const float4 v3 = r4[4 * lane + 3];

    // in-lane inclusive prefix of 16 elements
    float p[16];
    p[0]  = v0.x;          p[1]  = p[0]  + v0.y;
    p[2]  = p[1]  + v0.z;  p[3]  = p[2]  + v0.w;
    p[4]  = p[3]  + v1.x;  p[5]  = p[4]  + v1.y;
    p[6]  = p[5]  + v1.z;  p[7]  = p[6]  + v1.w;
    p[8]  = p[7]  + v2.x;  p[9]  = p[8]  + v2.y;
    p[10] = p[9]  + v2.z;  p[11] = p[10] + v2.w;
    p[12] = p[11] + v3.x;  p[13] = p[12] + v3.y;
    p[14] = p[13] + v3.z;  p[15] = p[14] + v3.w;

    // wave exclusive offset
    float inc = p[15];
#pragma unroll
    for (int d = 1; d < 64; d <<= 1) {
        const float u = __shfl_up(inc, d, 64);
        if (lane >= d) inc += u;
    }
    const float off = inc - p[15];

    float P[16];                        // inclusive prefix at col 16*lane+k
#pragma unroll
    for (int k = 0; k < 16; ++k) P[k] = off + p[k];

    // A_k = P_incl[j+99], j = 16*lane+k:
    //   k<=12 -> (lane+6, k+3);  k>=13 -> (lane+7, k-13)
    float A[16];
#pragma unroll
    for (int k = 0; k < 13; ++k) A[k] = __shfl(P[k + 3], lane + 6, 64);
#pragma unroll
    for (int k = 13; k < 16; ++k) A[k] = __shfl(P[k - 13], lane + 7, 64);
    const float Bm = __shfl(P[15], lane - 1, 64);   // P_incl[j-1] for k==0

    float Rv[16];                       // R[j] = P[j+99] - P[j-1]
    Rv[0] = A[0] - ((lane == 0) ? 0.f : Bm);
#pragma unroll
    for (int k = 1; k < 16; ++k) Rv[k] = A[k] - P[k - 1];
    // lanes 58..63 produce garbage (wrapped shuffles) at cols >= 928; never read.

    union { __half2 h2[8]; uint4 u4[2]; } pk;
#pragma unroll
    for (int i = 0; i < 8; ++i) pk.h2[i] = __floats2half2_rn(Rv[2 * i], Rv[2 * i + 1]);

    uint4* __restrict__ dst =
        (uint4*)((char*)R + ((size_t)g * RSTRIDE + (size_t)lane * 16) * sizeof(__half));
    dst[0] = pk.u4[0];
    dst[1] = pk.u4[1];
}

// ---------------- pass 2 ----------------
__global__ __launch_bounds__(256) void pass2_colwin(const __half* __restrict__ R,
                                                    float* __restrict__ out) {
    const int img   = (int)blockIdx.x;
    const int chunk = (int)blockIdx.y;
    const int t     = (int)threadIdx.x;
    const int j     = 4 * t;                    // output col base (stride-4)

    const int r0 = chunk * RP2;
    const int r1 = min(OH, r0 + RP2);

    const __half* __restrict__ Ri = R + (size_t)img * HH * RSTRIDE;
    float* __restrict__ oi        = out + (size_t)img * OH * OW;

    float w0 = 0.f, w1 = 0.f, w2 = 0.f, w3 = 0.f;
#pragma unroll 4
    for (int d = 0; d < KS; ++d) {
        union { uint2 u; __half2 h[2]; } q;
        q.u = *(const uint2*)(Ri + (size_t)(r0 + d) * RSTRIDE + j);
        const float2 a = __half22float2(q.h[0]);
        const float2 b = __half22float2(q.h[1]);
        w0 += a.x; w1 += a.y; w2 += b.x; w3 += b.y;
    }

    const int nv = OW - j;   // valid cols this thread (>=4 means full)

#define EMIT(ii)                                                         \
    do {                                                                 \
        float o0 = w0 * KVALF, o1 = w1 * KVALF,                          \
              o2 = w2 * KVALF, o3 = w3 * KVALF;                          \
        o0 = (o0 > THRESHF) ? 1.f : o0;  o1 = (o1 > THRESHF) ? 1.f : o1; \
        o2 = (o2 > THRESHF) ? 1.f : o2;  o3 = (o3 > THRESHF) ? 1.f : o3; \
        float* op = oi + (size_t)(ii) * OW + j;                          \
        if (nv > 0) op[0] = o0;                                          \
        if (nv > 1) op[1] = o1;                                          \
        if (nv > 2) op[2] = o2;                                          \
        if (nv > 3) op[3] = o3;                                          \
    } while (0)

    EMIT(r0);
#pragma unroll 2
    for (int i = r0 + 1; i < r1; ++i) {
        union { uint2 u; __half2 h[2]; } qn, qo;
        qn.u = *(const uint2*)(Ri + (size_t)(i + KS - 1) * RSTRIDE + j);
        qo.u = *(const uint2*)(Ri + (size_t)(i - 1) * RSTRIDE + j);
        const float2 na = __half22float2(qn.h[0]);
        const float2 nb = __half22float2(qn.h[1]);
        const float2 oa = __half22float2(qo.h[0]);
        const float2 ob = __half22float2(qo.h[1]);
        w0 += na.x - oa.x; w1 += na.y - oa.y;
        w2 += nb.x - ob.x; w3 += nb.y - ob.y;
        EMIT(i);
    }
#undef EMIT
}

// ---------------- fallback (R2 kernel, used only if ws too small) ----------------
#define SW      64
#define NSTRIP  15
#define NCHUNKF 12
#define RPCF    78
#define NWAVESF (NIMG * NSTRIP * NCHUNKF)

__global__ __launch_bounds__(256) void blur_wave(const float* __restrict__ x,
                                                 float* __restrict__ out) {
    const int lane = threadIdx.x & 63;
    const int wid  = threadIdx.x >> 6;
    const int w    = blockIdx.x * 4 + wid;

    const int strip = w % NSTRIP;
    const int chunk = (w / NSTRIP) % NCHUNKF;
    const int img   = w / (NSTRIP * NCHUNKF);

    const int j0     = strip * SW;
    const int jcount = min(SW, OW - j0);
    const int seg    = jcount + KS - 1;
    const bool h2    = (128 + lane) < seg;

    const int r0 = chunk * RPCF;
    const int r1 = min(OH, r0 + RPCF);

    const float* __restrict__ xi = x + (size_t)img * WW * WW + j0;
    float* __restrict__ oi       = out + (size_t)img * OH * OW;

    float cs0 = 0.f, cs1 = 0.f, cs2 = 0.f;
    for (int r = r0; r < r0 + KS; ++r) {
        const float* row = xi + (size_t)r * WW;
        cs0 += row[lane];
        cs1 += row[64 + lane];
        if (h2) cs2 += row[128 + lane];
    }

    for (int i = r0; i < r1; ++i) {
        const bool upd = (i + 1 < r1);
        float n0 = 0.f, n1 = 0.f, n2 = 0.f, o0 = 0.f, o1 = 0.f, o2 = 0.f;
        if (upd) {
            const float* rn = xi + (size_t)(i + KS) * WW;
            const float* ro = xi + (size_t)i * WW;
            n0 = rn[lane];      o0 = ro[lane];
            n1 = rn[64 + lane]; o1 = ro[64 + lane];
            if (h2) { n2 = rn[128 + lane]; o2 = ro[128 + lane]; }
        }

        float s0 = cs0, s1 = cs1, s2 = cs2;
#pragma unroll
        for (int d = 1; d < 64; d <<= 1) {
            const float u0 = __shfl_up(s0, d, 64);
            const float u1 = __shfl_up(s1, d, 64);
            const float u2 = __shfl_up(s2, d, 64);
            if (lane >= d) { s0 += u0; s1 += u1; s2 += u2; }
        }
        const float T0 = __shfl(s0, 63, 64);
        const float T1 = __shfl(s1, 63, 64);

        const float suf0 = T0 - (s0 - cs0);
        int srcA = lane + 35; if (srcA > 63) srcA = 63;
        int srcB = lane - 29; if (srcB < 0)  srcB = 0;
        const float a = __shfl(s1, srcA, 64);
        const float b = __shfl(s2, srcB, 64);

        float win;
        if (lane < 28)       win = suf0 + a;
        else if (lane == 28) win = suf0 + T1;
        else                 win = suf0 + T1 + b;

        if (lane < jcount) {
            const float v = KVALF * win;
            oi[(size_t)i * OW + (j0 + lane)] = (v > THRESHF) ? 1.0f : v;
        }

        if (upd) { cs0 += n0 - o0; cs1 += n1 - o1; cs2 += n2 - o2; }
    }
}

extern "C" void kernel_launch(void* const* d_in, const int* in_sizes, int n_in,
                              void* d_out, int out_size, void* d_ws, size_t ws_size,
                              hipStream_t stream) {
    const float* x = (const float*)d_in[0];
    float* out     = (float*)d_out;
    const size_t need = (size_t)NROWS * RSTRIDE * sizeof(__half);   // 48 MiB
    if (ws_size >= need) {
        __half* R = (__half*)d_ws;
        pass1_rowwin<<<dim3(NROWS / 4), dim3(256), 0, stream>>>(x, R);
        pass2_colwin<<<dim3(NIMG, NC2), dim3(256), 0, stream>>>(R, out);
    } else {
        blur_wave<<<dim3(NWAVESF / 4), dim3(256), 0, stream>>>(x, out);
    }
}